// Round 1
// baseline (2743.217 us; speedup 1.0000x reference)
//
#include <hip/hip_runtime.h>
#include <math.h>

#define N_   8
#define CIN  512
#define MID  256
#define OUTC 256
#define H_   56
#define W_   56
#define HW   3136
#define EPS  1e-5f

// workspace layout (in floats)
#define XF_NHWC_SZ  (N_*HW*MID)          // 6,422,528
#define OFF_SZ      (N_*HW*18)           // 451,584
#define WDT_OFF     (XF_NHWC_SZ + OFF_SZ)
// wdt: [o][k*256+c], 256*2304 floats

// ---------------- prep: transpose dcn_w [O][C][9] -> wdt [O][9][C] ----------------
__global__ __launch_bounds__(256) void prep_wdt(const float* __restrict__ dcn_w,
                                                float* __restrict__ wdt) {
  int e = blockIdx.x * 256 + threadIdx.x;   // < 589,824
  int o = e / 2304;
  int r = e - o * 2304;
  int k = r >> 8;          // 0..8
  int c = r & 255;
  wdt[e] = dcn_w[o * 2304 + c * 9 + k];
}

// ---------------- K1: conv1(1x1) + BN1 + upsample + attention -> xf ----------------
__global__ __launch_bounds__(256) void k1_conv1_attn(
    const float* __restrict__ x, const float* __restrict__ y,
    const float* __restrict__ conv1_w,
    const float* __restrict__ g1, const float* __restrict__ b1,
    const float* __restrict__ m1, const float* __restrict__ v1,
    const float* __restrict__ att_w, const float* __restrict__ att_b,
    float* __restrict__ xf_out,        // NCHW (second output)
    float* __restrict__ xf_nhwc) {     // NHWC scratch
  __shared__ float xs[32][16];
  __shared__ float xm_l[256][17];
  __shared__ float yu_l[256][17];
  __shared__ float red[2][16][9];
  __shared__ float z_l[2][16];

  const int t   = threadIdx.x;         // = output channel m
  const int n   = blockIdx.y;
  const int hw0 = blockIdx.x * 16;

  float acc[16];
  #pragma unroll
  for (int i = 0; i < 16; ++i) acc[i] = 0.f;

  const float* xb = x + (size_t)n * CIN * HW + hw0;

  for (int kc = 0; kc < CIN; kc += 32) {
    {
      int e = t, k = e >> 4, p = e & 15;
      xs[k][p] = xb[(kc + k) * HW + p];
      e = t + 256; k = e >> 4; p = e & 15;
      xs[k][p] = xb[(kc + k) * HW + p];
    }
    __syncthreads();
    const float4* wr = (const float4*)(conv1_w + t * CIN + kc);
    #pragma unroll
    for (int i = 0; i < 8; ++i) {
      float4 wv = wr[i];
      #pragma unroll
      for (int kk = 0; kk < 4; ++kk) {
        float wk = (kk == 0) ? wv.x : (kk == 1) ? wv.y : (kk == 2) ? wv.z : wv.w;
        const float4* xr4 = (const float4*)&xs[i * 4 + kk][0];   // broadcast reads
        #pragma unroll
        for (int j = 0; j < 4; ++j) {
          float4 xv = xr4[j];
          acc[j*4+0] = fmaf(wk, xv.x, acc[j*4+0]);
          acc[j*4+1] = fmaf(wk, xv.y, acc[j*4+1]);
          acc[j*4+2] = fmaf(wk, xv.z, acc[j*4+2]);
          acc[j*4+3] = fmaf(wk, xv.w, acc[j*4+3]);
        }
      }
    }
    __syncthreads();
  }

  // BN1
  float sc = g1[t] * rsqrtf(v1[t] + EPS);
  float sh = b1[t] - m1[t] * sc;
  float xm[16], yv[16];
  #pragma unroll
  for (int p = 0; p < 16; ++p) xm[p] = fmaf(acc[p], sc, sh);

  // nearest-upsampled y
  const float* yb = y + ((size_t)n * MID + t) * 784;
  #pragma unroll
  for (int p = 0; p < 16; ++p) {
    int pix = hw0 + p;
    int hh = pix / 56;
    int ww = pix - hh * 56;
    yv[p] = yb[(hh >> 1) * 28 + (ww >> 1)];
  }

  #pragma unroll
  for (int p = 0; p < 16; ++p) { xm_l[t][p] = xm[p]; yu_l[t][p] = yv[p]; }
  __syncthreads();

  // attention partials: thread -> (o, p, seg)
  {
    int o = t >> 7, p = (t >> 3) & 15, seg = t & 7;
    const float* aw = att_w + o * 512 + seg * 32;
    float s = 0.f;
    #pragma unroll 8
    for (int i = 0; i < 32; ++i) {
      int mm = seg * 32 + i;
      s = fmaf(aw[i], xm_l[mm][p], s);
      s = fmaf(aw[256 + i], yu_l[mm][p], s);
    }
    red[o][p][seg] = s;
  }
  __syncthreads();
  if (t < 32) {
    int o = t >> 4, p = t & 15;
    float s = att_b[o];
    #pragma unroll
    for (int g = 0; g < 8; ++g) s += red[o][p][g];
    z_l[o][p] = 1.f / (1.f + expf(-s));
  }
  __syncthreads();

  float xf[16];
  #pragma unroll
  for (int p = 0; p < 16; ++p) xf[p] = xm[p] * z_l[0][p] + yv[p] * z_l[1][p];

  // NCHW output (this IS output #2)
  float* ob = xf_out + ((size_t)n * MID + t) * HW + hw0;
  #pragma unroll
  for (int j = 0; j < 4; ++j) {
    float4 v; v.x = xf[j*4]; v.y = xf[j*4+1]; v.z = xf[j*4+2]; v.w = xf[j*4+3];
    ((float4*)ob)[j] = v;
  }
  // NHWC scratch (coalesced over m)
  float* nb = xf_nhwc + ((size_t)n * HW + hw0) * MID + t;
  #pragma unroll
  for (int p = 0; p < 16; ++p) nb[p * MID] = xf[p];
}

// ---------------- K2: 3x3 conv -> 18 offset channels ----------------
__global__ __launch_bounds__(256) void k2_offconv(
    const float* __restrict__ xf_nhwc, const float* __restrict__ off_w,
    float* __restrict__ off_out) {     // [n][h][w][18]
  __shared__ float xs[3][58][36];      // 3 rows x (w=-1..56) x c-chunk(32), pad 36
  __shared__ float wl[18][9][32];
  __shared__ float red[4][56][19];

  const int t = threadIdx.x;
  const int n = blockIdx.x / 56;
  const int h = blockIdx.x % 56;
  const int wq   = t % 56;
  const int cseg = t / 56;             // 0..3 active
  const bool act = (t < 224);

  float4 acc4[18];
  #pragma unroll
  for (int o = 0; o < 18; ++o) { acc4[o].x = 0; acc4[o].y = 0; acc4[o].z = 0; acc4[o].w = 0; }

  for (int c0 = 0; c0 < 256; c0 += 32) {
    for (int e = t; e < 3 * 58 * 32; e += 256) {
      int ky = e / (58 * 32);
      int r  = e - ky * (58 * 32);
      int wx = r >> 5;
      int cc = r & 31;
      int yy = h - 1 + ky;
      int xx = wx - 1;
      float v = 0.f;
      if ((unsigned)yy < 56u && (unsigned)xx < 56u)
        v = xf_nhwc[((n * HW) + yy * 56 + xx) * MID + c0 + cc];
      xs[ky][wx][cc] = v;
    }
    for (int e = t; e < 18 * 9 * 32; e += 256) {
      int o   = e / 288;
      int r   = e - o * 288;
      int tap = r >> 5;
      int cc  = r & 31;
      wl[o][tap][cc] = off_w[(o * 256 + c0 + cc) * 9 + tap];
    }
    __syncthreads();
    if (act) {
      #pragma unroll
      for (int c4 = 0; c4 < 2; ++c4) {
        const int cc = cseg * 8 + c4 * 4;
        float4 win[9];
        #pragma unroll
        for (int tap = 0; tap < 9; ++tap) {
          int ky = tap / 3, kx = tap - (tap / 3) * 3;
          win[tap] = *(const float4*)&xs[ky][wq + kx][cc];
        }
        #pragma unroll
        for (int o = 0; o < 18; ++o) {
          float4 a = acc4[o];
          #pragma unroll
          for (int tap = 0; tap < 9; ++tap) {
            float4 wv = *(const float4*)&wl[o][tap][cc];
            a.x = fmaf(win[tap].x, wv.x, a.x);
            a.y = fmaf(win[tap].y, wv.y, a.y);
            a.z = fmaf(win[tap].z, wv.z, a.z);
            a.w = fmaf(win[tap].w, wv.w, a.w);
          }
          acc4[o] = a;
        }
      }
    }
    __syncthreads();
  }
  if (act) {
    #pragma unroll
    for (int o = 0; o < 18; ++o)
      red[cseg][wq][o] = acc4[o].x + acc4[o].y + acc4[o].z + acc4[o].w;
  }
  __syncthreads();
  for (int e = t; e < 56 * 18; e += 256) {
    int ww = e / 18;
    int o  = e - ww * 18;
    float s = red[0][ww][o] + red[1][ww][o] + red[2][ww][o] + red[3][ww][o];
    off_out[((n * HW) + h * 56 + ww) * 18 + o] = s;
  }
}

// ---------------- K3: deformable conv + BN2 ----------------
__global__ __launch_bounds__(256) void k3_deform(
    const float* __restrict__ xf_nhwc, const float* __restrict__ off_in,
    const float* __restrict__ wdt,
    const float* __restrict__ g2, const float* __restrict__ b2,
    const float* __restrict__ m2, const float* __restrict__ v2,
    float* __restrict__ out) {
  __shared__ float S[8 * 2304];        // sampled [pix][k*256+c]
  __shared__ float cw[72][4];
  __shared__ int   ci[72][2];
  __shared__ float offs[8][18];

  const int t    = threadIdx.x;
  const int n    = blockIdx.x / 392;
  const int pix0 = (blockIdx.x % 392) * 8;

  if (t < 144) {
    int p = t / 18, j = t - p * 18;
    offs[p][j] = off_in[((n * HW) + pix0 + p) * 18 + j];
  }
  __syncthreads();
  if (t < 72) {
    int p = t / 9, k = t - p * 9;
    int ky = k / 3, kx = k - ky * 3;
    int pix = pix0 + p;
    int hh = pix / 56, ww = pix - hh * 56;
    float sy = (float)(hh - 1 + ky) + offs[p][2 * k];
    float sx = (float)(ww - 1 + kx) + offs[p][2 * k + 1];
    float y0f = floorf(sy), x0f = floorf(sx);
    float wy = sy - y0f, wx = sx - x0f;
    ci[t][0] = (int)y0f;
    ci[t][1] = (int)x0f;
    float iy = 1.f - wy, ix = 1.f - wx;
    cw[t][0] = iy * ix; cw[t][1] = iy * wx; cw[t][2] = wy * ix; cw[t][3] = wy * wx;
  }
  __syncthreads();

  // build S: thread = channel c (coalesced NHWC gathers)
  {
    const float* xfb = xf_nhwc + (size_t)n * HW * MID;
    const int c = t;
    for (int s = 0; s < 72; ++s) {
      int y0 = ci[s][0], x0 = ci[s][1];
      float w00 = cw[s][0], w01 = cw[s][1], w10 = cw[s][2], w11 = cw[s][3];
      float v = 0.f;
      bool yv0 = (unsigned)y0 < 56u, yv1 = (unsigned)(y0 + 1) < 56u;
      bool xv0 = (unsigned)x0 < 56u, xv1 = (unsigned)(x0 + 1) < 56u;
      if (yv0 && xv0) v = fmaf(w00, xfb[(y0 * 56 + x0) * MID + c], v);
      if (yv0 && xv1) v = fmaf(w01, xfb[(y0 * 56 + x0 + 1) * MID + c], v);
      if (yv1 && xv0) v = fmaf(w10, xfb[((y0 + 1) * 56 + x0) * MID + c], v);
      if (yv1 && xv1) v = fmaf(w11, xfb[((y0 + 1) * 56 + x0 + 1) * MID + c], v);
      int p = s / 9, k = s - p * 9;
      S[p * 2304 + k * 256 + c] = v;
    }
  }
  __syncthreads();

  // einsum: thread -> (o pair, 4 pixels). S reads are wave-broadcast.
  {
    const int half = t >> 7;
    const int o0 = (t & 127) * 2;
    float a00 = 0, a01 = 0, a02 = 0, a03 = 0;
    float a10 = 0, a11 = 0, a12 = 0, a13 = 0;
    const float4* wa = (const float4*)(wdt + o0 * 2304);
    const float4* wb = (const float4*)(wdt + (o0 + 1) * 2304);
    const float4* s0 = (const float4*)(S + (half * 4 + 0) * 2304);
    const float4* s1 = (const float4*)(S + (half * 4 + 1) * 2304);
    const float4* s2 = (const float4*)(S + (half * 4 + 2) * 2304);
    const float4* s3 = (const float4*)(S + (half * 4 + 3) * 2304);
    #pragma unroll 2
    for (int jg = 0; jg < 576; ++jg) {
      float4 a = wa[jg], b = wb[jg];
      float4 v0 = s0[jg], v1 = s1[jg], v2 = s2[jg], v3 = s3[jg];
      a00 = fmaf(a.x, v0.x, a00); a00 = fmaf(a.y, v0.y, a00); a00 = fmaf(a.z, v0.z, a00); a00 = fmaf(a.w, v0.w, a00);
      a01 = fmaf(a.x, v1.x, a01); a01 = fmaf(a.y, v1.y, a01); a01 = fmaf(a.z, v1.z, a01); a01 = fmaf(a.w, v1.w, a01);
      a02 = fmaf(a.x, v2.x, a02); a02 = fmaf(a.y, v2.y, a02); a02 = fmaf(a.z, v2.z, a02); a02 = fmaf(a.w, v2.w, a02);
      a03 = fmaf(a.x, v3.x, a03); a03 = fmaf(a.y, v3.y, a03); a03 = fmaf(a.z, v3.z, a03); a03 = fmaf(a.w, v3.w, a03);
      a10 = fmaf(b.x, v0.x, a10); a10 = fmaf(b.y, v0.y, a10); a10 = fmaf(b.z, v0.z, a10); a10 = fmaf(b.w, v0.w, a10);
      a11 = fmaf(b.x, v1.x, a11); a11 = fmaf(b.y, v1.y, a11); a11 = fmaf(b.z, v1.z, a11); a11 = fmaf(b.w, v1.w, a11);
      a12 = fmaf(b.x, v2.x, a12); a12 = fmaf(b.y, v2.y, a12); a12 = fmaf(b.z, v2.z, a12); a12 = fmaf(b.w, v2.w, a12);
      a13 = fmaf(b.x, v3.x, a13); a13 = fmaf(b.y, v3.y, a13); a13 = fmaf(b.z, v3.z, a13); a13 = fmaf(b.w, v3.w, a13);
    }
    float accs[2][4] = {{a00, a01, a02, a03}, {a10, a11, a12, a13}};
    #pragma unroll
    for (int j = 0; j < 2; ++j) {
      int o = o0 + j;
      float scv = g2[o] * rsqrtf(v2[o] + EPS);
      float shv = b2[o] - m2[o] * scv;
      float* ob = out + ((size_t)n * OUTC + o) * HW + pix0 + half * 4;
      #pragma unroll
      for (int p = 0; p < 4; ++p) ob[p] = fmaf(accs[j][p], scv, shv);
    }
  }
}

extern "C" void kernel_launch(void* const* d_in, const int* in_sizes, int n_in,
                              void* d_out, int out_size, void* d_ws, size_t ws_size,
                              hipStream_t stream) {
  const float* x       = (const float*)d_in[0];
  const float* y       = (const float*)d_in[1];
  const float* conv1_w = (const float*)d_in[2];
  const float* g1      = (const float*)d_in[3];
  const float* b1      = (const float*)d_in[4];
  const float* m1      = (const float*)d_in[5];
  const float* v1      = (const float*)d_in[6];
  const float* att_w   = (const float*)d_in[7];
  const float* att_b   = (const float*)d_in[8];
  const float* off_w   = (const float*)d_in[9];
  const float* dcn_w   = (const float*)d_in[10];
  const float* g2      = (const float*)d_in[11];
  const float* b2      = (const float*)d_in[12];
  const float* m2      = (const float*)d_in[13];
  const float* v2      = (const float*)d_in[14];

  float* out     = (float*)d_out;
  float* xf_out  = out + (size_t)N_ * OUTC * HW;   // second output region
  float* ws      = (float*)d_ws;
  float* xf_nhwc = ws;
  float* off_buf = ws + XF_NHWC_SZ;
  float* wdt     = ws + WDT_OFF;

  hipLaunchKernelGGL(prep_wdt, dim3(2304), dim3(256), 0, stream, dcn_w, wdt);
  hipLaunchKernelGGL(k1_conv1_attn, dim3(196, N_), dim3(256), 0, stream,
                     x, y, conv1_w, g1, b1, m1, v1, att_w, att_b, xf_out, xf_nhwc);
  hipLaunchKernelGGL(k2_offconv, dim3(448), dim3(256), 0, stream,
                     xf_nhwc, off_w, off_buf);
  hipLaunchKernelGGL(k3_deform, dim3(3136), dim3(256), 0, stream,
                     xf_nhwc, off_buf, wdt, g2, b2, m2, v2, out);
}

// Round 2
// 1158.977 us; speedup vs baseline: 2.3669x; 2.3669x over previous
//
#include <hip/hip_runtime.h>
#include <math.h>

#define N_   8
#define CIN  512
#define MID  256
#define OUTC 256
#define H_   56
#define W_   56
#define HW   3136
#define EPS  1e-5f

typedef __attribute__((ext_vector_type(8))) short short8;
typedef __attribute__((ext_vector_type(4))) float floatx4;

__device__ __forceinline__ float bf2f(unsigned short b) {
  unsigned int u = ((unsigned int)b) << 16;
  return __builtin_bit_cast(float, u);
}
__device__ __forceinline__ unsigned short f2bf(float f) {
  unsigned int u = __builtin_bit_cast(unsigned int, f);
  unsigned int r = u + 0x7fffu + ((u >> 16) & 1u);
  return (unsigned short)(r >> 16);
}

// workspace layout (bytes)
//   xf_bf  : bf16 NHWC  N*HW*MID*2        = 12,845,056
//   off    : fp32       N*HW*18*4         =  1,806,336
//   wbf    : bf16       256*2304*2        =  1,179,648   layout [r/8][o][8]
#define XF_BF_BYTES  (N_*HW*MID*2)
#define OFF_BYTES    (N_*HW*18*4)

// ---------------- prep: dcn_w [O][C][9] -> wbf bf16 [r/8][o][j] (r = tap*256+c) ----
__global__ __launch_bounds__(256) void prep_wbf(const float* __restrict__ dcn_w,
                                                unsigned short* __restrict__ wbf) {
  int e = blockIdx.x * 256 + threadIdx.x;   // < 589,824
  int rb  = e >> 11;          // / 2048
  int rem = e & 2047;
  int o   = rem >> 3;
  int j   = e & 7;
  int r   = rb * 8 + j;
  int tap = r >> 8;
  int c   = r & 255;
  wbf[e] = f2bf(dcn_w[(o * 256 + c) * 9 + tap]);
}

// ---------------- K1: conv1(1x1) + BN1 + upsample + attention -> xf ----------------
__global__ __launch_bounds__(256) void k1_conv1_attn(
    const float* __restrict__ x, const float* __restrict__ y,
    const float* __restrict__ conv1_w,
    const float* __restrict__ g1, const float* __restrict__ b1,
    const float* __restrict__ m1, const float* __restrict__ v1,
    const float* __restrict__ att_w, const float* __restrict__ att_b,
    float* __restrict__ xf_out,              // NCHW fp32 (second output)
    unsigned short* __restrict__ xf_bf) {    // NHWC bf16 scratch
  __shared__ float xs[32][16];
  __shared__ float xm_l[256][17];
  __shared__ float yu_l[256][17];
  __shared__ float red[2][16][9];
  __shared__ float z_l[2][16];

  const int t   = threadIdx.x;         // = output channel m
  const int n   = blockIdx.y;
  const int hw0 = blockIdx.x * 16;

  float acc[16];
  #pragma unroll
  for (int i = 0; i < 16; ++i) acc[i] = 0.f;

  const float* xb = x + (size_t)n * CIN * HW + hw0;

  for (int kc = 0; kc < CIN; kc += 32) {
    {
      int e = t, k = e >> 4, p = e & 15;
      xs[k][p] = xb[(kc + k) * HW + p];
      e = t + 256; k = e >> 4; p = e & 15;
      xs[k][p] = xb[(kc + k) * HW + p];
    }
    __syncthreads();
    const float4* wr = (const float4*)(conv1_w + t * CIN + kc);
    #pragma unroll
    for (int i = 0; i < 8; ++i) {
      float4 wv = wr[i];
      #pragma unroll
      for (int kk = 0; kk < 4; ++kk) {
        float wk = (kk == 0) ? wv.x : (kk == 1) ? wv.y : (kk == 2) ? wv.z : wv.w;
        const float4* xr4 = (const float4*)&xs[i * 4 + kk][0];
        #pragma unroll
        for (int j = 0; j < 4; ++j) {
          float4 xv = xr4[j];
          acc[j*4+0] = fmaf(wk, xv.x, acc[j*4+0]);
          acc[j*4+1] = fmaf(wk, xv.y, acc[j*4+1]);
          acc[j*4+2] = fmaf(wk, xv.z, acc[j*4+2]);
          acc[j*4+3] = fmaf(wk, xv.w, acc[j*4+3]);
        }
      }
    }
    __syncthreads();
  }

  float sc = g1[t] * rsqrtf(v1[t] + EPS);
  float sh = b1[t] - m1[t] * sc;
  float xm[16], yv[16];
  #pragma unroll
  for (int p = 0; p < 16; ++p) xm[p] = fmaf(acc[p], sc, sh);

  const float* yb = y + ((size_t)n * MID + t) * 784;
  #pragma unroll
  for (int p = 0; p < 16; ++p) {
    int pix = hw0 + p;
    int hh = pix / 56;
    int ww = pix - hh * 56;
    yv[p] = yb[(hh >> 1) * 28 + (ww >> 1)];
  }

  #pragma unroll
  for (int p = 0; p < 16; ++p) { xm_l[t][p] = xm[p]; yu_l[t][p] = yv[p]; }
  __syncthreads();

  {
    int o = t >> 7, p = (t >> 3) & 15, seg = t & 7;
    const float* aw = att_w + o * 512 + seg * 32;
    float s = 0.f;
    #pragma unroll 8
    for (int i = 0; i < 32; ++i) {
      int mm = seg * 32 + i;
      s = fmaf(aw[i], xm_l[mm][p], s);
      s = fmaf(aw[256 + i], yu_l[mm][p], s);
    }
    red[o][p][seg] = s;
  }
  __syncthreads();
  if (t < 32) {
    int o = t >> 4, p = t & 15;
    float s = att_b[o];
    #pragma unroll
    for (int g = 0; g < 8; ++g) s += red[o][p][g];
    z_l[o][p] = 1.f / (1.f + expf(-s));
  }
  __syncthreads();

  float xf[16];
  #pragma unroll
  for (int p = 0; p < 16; ++p) xf[p] = xm[p] * z_l[0][p] + yv[p] * z_l[1][p];

  float* ob = xf_out + ((size_t)n * MID + t) * HW + hw0;
  #pragma unroll
  for (int j = 0; j < 4; ++j) {
    float4 v; v.x = xf[j*4]; v.y = xf[j*4+1]; v.z = xf[j*4+2]; v.w = xf[j*4+3];
    ((float4*)ob)[j] = v;
  }
  unsigned short* nb = xf_bf + ((size_t)n * HW + hw0) * MID + t;
  #pragma unroll
  for (int p = 0; p < 16; ++p) nb[p * MID] = f2bf(xf[p]);
}

// ---------------- K2: 3x3 conv -> 18 offset channels ----------------
__global__ __launch_bounds__(256) void k2_offconv(
    const unsigned short* __restrict__ xf_bf, const float* __restrict__ off_w,
    float* __restrict__ off_out) {     // [n][h][w][18]
  __shared__ float xs[3][58][36];
  __shared__ float wl[18][9][32];
  __shared__ float red[4][56][19];

  const int t = threadIdx.x;
  const int n = blockIdx.x / 56;
  const int h = blockIdx.x % 56;
  const int wq   = t % 56;
  const int cseg = t / 56;
  const bool act = (t < 224);

  float4 acc4[18];
  #pragma unroll
  for (int o = 0; o < 18; ++o) { acc4[o].x = 0; acc4[o].y = 0; acc4[o].z = 0; acc4[o].w = 0; }

  for (int c0 = 0; c0 < 256; c0 += 32) {
    for (int e = t; e < 3 * 58 * 32; e += 256) {
      int ky = e / (58 * 32);
      int r  = e - ky * (58 * 32);
      int wx = r >> 5;
      int cc = r & 31;
      int yy = h - 1 + ky;
      int xx = wx - 1;
      float v = 0.f;
      if ((unsigned)yy < 56u && (unsigned)xx < 56u)
        v = bf2f(xf_bf[((n * HW) + yy * 56 + xx) * MID + c0 + cc]);
      xs[ky][wx][cc] = v;
    }
    for (int e = t; e < 18 * 9 * 32; e += 256) {
      int o   = e / 288;
      int r   = e - o * 288;
      int tap = r >> 5;
      int cc  = r & 31;
      wl[o][tap][cc] = off_w[(o * 256 + c0 + cc) * 9 + tap];
    }
    __syncthreads();
    if (act) {
      #pragma unroll
      for (int c4 = 0; c4 < 2; ++c4) {
        const int cc = cseg * 8 + c4 * 4;
        float4 win[9];
        #pragma unroll
        for (int tap = 0; tap < 9; ++tap) {
          int ky = tap / 3, kx = tap - (tap / 3) * 3;
          win[tap] = *(const float4*)&xs[ky][wq + kx][cc];
        }
        #pragma unroll
        for (int o = 0; o < 18; ++o) {
          float4 a = acc4[o];
          #pragma unroll
          for (int tap = 0; tap < 9; ++tap) {
            float4 wv = *(const float4*)&wl[o][tap][cc];
            a.x = fmaf(win[tap].x, wv.x, a.x);
            a.y = fmaf(win[tap].y, wv.y, a.y);
            a.z = fmaf(win[tap].z, wv.z, a.z);
            a.w = fmaf(win[tap].w, wv.w, a.w);
          }
          acc4[o] = a;
        }
      }
    }
    __syncthreads();
  }
  if (act) {
    #pragma unroll
    for (int o = 0; o < 18; ++o)
      red[cseg][wq][o] = acc4[o].x + acc4[o].y + acc4[o].z + acc4[o].w;
  }
  __syncthreads();
  for (int e = t; e < 56 * 18; e += 256) {
    int ww = e / 18;
    int o  = e - ww * 18;
    float s = red[0][ww][o] + red[1][ww][o] + red[2][ww][o] + red[3][ww][o];
    off_out[((n * HW) + h * 56 + ww) * 18 + o] = s;
  }
}

// ---------------- K3: deformable conv + BN2, bf16 MFMA ----------------
// Per block: 32 pixels, all 256 outputs. Per tap: sample 32x256 slab -> LDS bf16,
// then GEMM K=256 via mfma_f32_16x16x32_bf16. W in wbf [r/8][o][8] (A-frag layout).
#define PB 32
#define SPITCH 264   // bf16 elements per pixel row (256 + 8 pad)

__global__ __launch_bounds__(256) void k3_deform_mfma(
    const unsigned short* __restrict__ xf_bf, const float* __restrict__ off_in,
    const unsigned short* __restrict__ wbf,
    const float* __restrict__ g2, const float* __restrict__ b2,
    const float* __restrict__ m2, const float* __restrict__ v2,
    float* __restrict__ out) {
  __shared__ unsigned short S[PB * SPITCH];   // 16,896 B
  __shared__ float cw[288][4];                // 4,608 B
  __shared__ int   ad[288][4];                // 4,608 B  (element offsets; 0 if invalid)
  __shared__ float offs[PB * 18];             // 2,304 B

  const int t    = threadIdx.x;
  const int n    = blockIdx.x / 98;
  const int pix0 = (blockIdx.x % 98) * PB;

  for (int e = t; e < PB * 18; e += 256)
    offs[e] = off_in[((size_t)(n * HW) + pix0) * 18 + e];
  __syncthreads();

  for (int e = t; e < 288; e += 256) {
    int p = e / 9, k = e - p * 9;
    int ky = k / 3, kx = k - ky * 3;
    int pix = pix0 + p;
    int hh = pix / 56, ww = pix - hh * 56;
    float sy = (float)(hh - 1 + ky) + offs[p * 18 + 2 * k];
    float sx = (float)(ww - 1 + kx) + offs[p * 18 + 2 * k + 1];
    float y0f = floorf(sy), x0f = floorf(sx);
    int y0 = (int)y0f, x0 = (int)x0f;
    float wy = sy - y0f, wx = sx - x0f;
    float w00 = (1.f - wy) * (1.f - wx), w01 = (1.f - wy) * wx;
    float w10 = wy * (1.f - wx),         w11 = wy * wx;
    bool yv0 = (unsigned)y0 < 56u, yv1 = (unsigned)(y0 + 1) < 56u;
    bool xv0 = (unsigned)x0 < 56u, xv1 = (unsigned)(x0 + 1) < 56u;
    int base = n * HW;
    ad[e][0] = (yv0 && xv0) ? (base + y0 * 56 + x0) * 256       : 0;
    ad[e][1] = (yv0 && xv1) ? (base + y0 * 56 + x0 + 1) * 256   : 0;
    ad[e][2] = (yv1 && xv0) ? (base + (y0+1) * 56 + x0) * 256   : 0;
    ad[e][3] = (yv1 && xv1) ? (base + (y0+1) * 56 + x0 + 1) * 256 : 0;
    cw[e][0] = (yv0 && xv0) ? w00 : 0.f;
    cw[e][1] = (yv0 && xv1) ? w01 : 0.f;
    cw[e][2] = (yv1 && xv0) ? w10 : 0.f;
    cw[e][3] = (yv1 && xv1) ? w11 : 0.f;
  }

  const int w  = t >> 6;           // wave 0..3 -> o range [w*64, w*64+64)
  const int l  = t & 63;
  const int lo = l & 15;
  const int hi = l >> 4;           // 0..3

  floatx4 acc[4][2];
  #pragma unroll
  for (int i = 0; i < 4; ++i)
    #pragma unroll
    for (int j = 0; j < 2; ++j)
      acc[i][j] = (floatx4){0.f, 0.f, 0.f, 0.f};

  const short8* wbase = (const short8*)wbf;

  for (int tap = 0; tap < 9; ++tap) {
    __syncthreads();
    // sample: thread = channel c = t, 32 pixels for this tap
    #pragma unroll 4
    for (int p = 0; p < PB; ++p) {
      int s = p * 9 + tap;
      int a0 = ad[s][0], a1 = ad[s][1], a2 = ad[s][2], a3 = ad[s][3];
      float w0 = cw[s][0], w1 = cw[s][1], w2 = cw[s][2], w3 = cw[s][3];
      float v;
      v = w0 * bf2f(xf_bf[a0 + t]);
      v = fmaf(w1, bf2f(xf_bf[a1 + t]), v);
      v = fmaf(w2, bf2f(xf_bf[a2 + t]), v);
      v = fmaf(w3, bf2f(xf_bf[a3 + t]), v);
      S[p * SPITCH + t] = f2bf(v);
    }
    __syncthreads();

    // GEMM over this tap's K=256 (8 K-steps of 32)
    #pragma unroll
    for (int ks = 0; ks < 8; ++ks) {
      int rb = tap * 32 + ks * 4 + hi;
      const short8* wp = wbase + ((rb << 8) + (w << 6) + lo);
      short8 wa0 = wp[0];
      short8 wa1 = wp[16];
      short8 wa2 = wp[32];
      short8 wa3 = wp[48];
      const unsigned short* sp = &S[lo * SPITCH + (ks << 5) + (hi << 3)];
      short8 sb0 = *(const short8*)sp;
      short8 sb1 = *(const short8*)(sp + 16 * SPITCH);
      acc[0][0] = __builtin_amdgcn_mfma_f32_16x16x32_bf16(wa0, sb0, acc[0][0], 0, 0, 0);
      acc[0][1] = __builtin_amdgcn_mfma_f32_16x16x32_bf16(wa0, sb1, acc[0][1], 0, 0, 0);
      acc[1][0] = __builtin_amdgcn_mfma_f32_16x16x32_bf16(wa1, sb0, acc[1][0], 0, 0, 0);
      acc[1][1] = __builtin_amdgcn_mfma_f32_16x16x32_bf16(wa1, sb1, acc[1][1], 0, 0, 0);
      acc[2][0] = __builtin_amdgcn_mfma_f32_16x16x32_bf16(wa2, sb0, acc[2][0], 0, 0, 0);
      acc[2][1] = __builtin_amdgcn_mfma_f32_16x16x32_bf16(wa2, sb1, acc[2][1], 0, 0, 0);
      acc[3][0] = __builtin_amdgcn_mfma_f32_16x16x32_bf16(wa3, sb0, acc[3][0], 0, 0, 0);
      acc[3][1] = __builtin_amdgcn_mfma_f32_16x16x32_bf16(wa3, sb1, acc[3][1], 0, 0, 0);
    }
  }

  // epilogue: BN2 + coalesced stores. D: row(o)=hi*4+reg, col(pix)=lo
  #pragma unroll
  for (int i = 0; i < 4; ++i) {
    #pragma unroll
    for (int r = 0; r < 4; ++r) {
      int o = (w << 6) + (i << 4) + (hi << 2) + r;
      float scv = g2[o] * rsqrtf(v2[o] + EPS);
      float shv = b2[o] - m2[o] * scv;
      float* ob = out + ((size_t)(n * OUTC + o)) * HW + pix0;
      ob[lo]      = fmaf(acc[i][0][r], scv, shv);
      ob[16 + lo] = fmaf(acc[i][1][r], scv, shv);
    }
  }
}

extern "C" void kernel_launch(void* const* d_in, const int* in_sizes, int n_in,
                              void* d_out, int out_size, void* d_ws, size_t ws_size,
                              hipStream_t stream) {
  const float* x       = (const float*)d_in[0];
  const float* y       = (const float*)d_in[1];
  const float* conv1_w = (const float*)d_in[2];
  const float* g1      = (const float*)d_in[3];
  const float* b1      = (const float*)d_in[4];
  const float* m1      = (const float*)d_in[5];
  const float* v1      = (const float*)d_in[6];
  const float* att_w   = (const float*)d_in[7];
  const float* att_b   = (const float*)d_in[8];
  const float* off_w   = (const float*)d_in[9];
  const float* dcn_w   = (const float*)d_in[10];
  const float* g2      = (const float*)d_in[11];
  const float* b2      = (const float*)d_in[12];
  const float* m2      = (const float*)d_in[13];
  const float* v2      = (const float*)d_in[14];

  float* out    = (float*)d_out;
  float* xf_out = out + (size_t)N_ * OUTC * HW;

  char* ws = (char*)d_ws;
  unsigned short* xf_bf  = (unsigned short*)ws;
  float*          off_buf = (float*)(ws + XF_BF_BYTES);
  unsigned short* wbf    = (unsigned short*)(ws + XF_BF_BYTES + OFF_BYTES);

  hipLaunchKernelGGL(prep_wbf, dim3(2304), dim3(256), 0, stream, dcn_w, wbf);
  hipLaunchKernelGGL(k1_conv1_attn, dim3(196, N_), dim3(256), 0, stream,
                     x, y, conv1_w, g1, b1, m1, v1, att_w, att_b, xf_out, xf_bf);
  hipLaunchKernelGGL(k2_offconv, dim3(448), dim3(256), 0, stream,
                     xf_bf, off_w, off_buf);
  hipLaunchKernelGGL(k3_deform_mfma, dim3(784), dim3(256), 0, stream,
                     xf_bf, off_buf, wbf, g2, b2, m2, v2, out);
}

// Round 3
// 403.432 us; speedup vs baseline: 6.7997x; 2.8728x over previous
//
#include <hip/hip_runtime.h>
#include <math.h>

#define N_   8
#define CIN  512
#define MID  256
#define OUTC 256
#define H_   56
#define W_   56
#define HW   3136
#define EPS  1e-5f

typedef __attribute__((ext_vector_type(8))) short short8;
typedef __attribute__((ext_vector_type(4))) float floatx4;

__device__ __forceinline__ float bf2f(unsigned short b) {
  unsigned int u = ((unsigned int)b) << 16;
  return __builtin_bit_cast(float, u);
}
__device__ __forceinline__ unsigned short f2bf(float f) {
  unsigned int u = __builtin_bit_cast(unsigned int, f);
  unsigned int r = u + 0x7fffu + ((u >> 16) & 1u);
  return (unsigned short)(r >> 16);
}
// RNE-pack two floats into one dword of 2 bf16 (f0 -> low, f1 -> high)
__device__ __forceinline__ unsigned int pack2bf(float f0, float f1) {
  unsigned int u0 = __builtin_bit_cast(unsigned int, f0);
  unsigned int u1 = __builtin_bit_cast(unsigned int, f1);
  u0 += 0x7fffu + ((u0 >> 16) & 1u);
  u1 += 0x7fffu + ((u1 >> 16) & 1u);
  return (u0 >> 16) | (u1 & 0xffff0000u);
}

// workspace layout (bytes)
//   xf_bf : bf16 NHWC  N*HW*MID*2   = 12,845,056
//   off   : fp32       N*HW*18*4    =  1,806,336
//   wbf   : bf16       256*2304*2   =  1,179,648   (k3 weights, [r/8][o][8])
//   wk2   : bf16       2*72*64*8*2  =    147,456   (k2 weights, A-frag layout)
#define XF_BF_BYTES  (N_*HW*MID*2)
#define OFF_BYTES    (N_*HW*18*4)
#define WBF_BYTES    (256*2304*2)

// ---------------- prep: dcn_w [O][C][9] -> wbf bf16 [r/8][o][j] (r = tap*256+c) ----
__global__ __launch_bounds__(256) void prep_wbf(const float* __restrict__ dcn_w,
                                                unsigned short* __restrict__ wbf) {
  int e = blockIdx.x * 256 + threadIdx.x;   // < 589,824
  int rb  = e >> 11;
  int rem = e & 2047;
  int o   = rem >> 3;
  int j   = e & 7;
  int r   = rb * 8 + j;
  int tap = r >> 8;
  int c   = r & 255;
  wbf[e] = f2bf(dcn_w[(o * 256 + c) * 9 + tap]);
}

// ---------------- prep: off_w [18][256][3][3] -> wk2 A-frag layout ----------------
// wk2[((ot*72 + ks)*64 + l)*8 + j]: o = ot*16 + (l&15), r = ks*32 + (l>>4)*8 + j,
// tap = r>>8, c = r&255; zero for o >= 18.
__global__ __launch_bounds__(256) void prep_wk2(const float* __restrict__ off_w,
                                                unsigned short* __restrict__ wk2) {
  int e = blockIdx.x * 256 + threadIdx.x;   // < 73,728
  int j  = e & 7;
  int l  = (e >> 3) & 63;
  int q  = e >> 9;              // 0..143
  int ot = (q >= 72) ? 1 : 0;
  int ks = q - ot * 72;
  int o  = ot * 16 + (l & 15);
  int r  = ks * 32 + ((l >> 4) << 3) + j;
  int tap = r >> 8;
  int c   = r & 255;
  float v = (o < 18) ? off_w[(o * 256 + c) * 9 + tap] : 0.f;
  wk2[e] = f2bf(v);
}

// ---------------- K1: conv1(1x1) + BN1 + upsample + attention -> xf ----------------
__global__ __launch_bounds__(256) void k1_conv1_attn(
    const float* __restrict__ x, const float* __restrict__ y,
    const float* __restrict__ conv1_w,
    const float* __restrict__ g1, const float* __restrict__ b1,
    const float* __restrict__ m1, const float* __restrict__ v1,
    const float* __restrict__ att_w, const float* __restrict__ att_b,
    float* __restrict__ xf_out,              // NCHW fp32 (second output)
    unsigned short* __restrict__ xf_bf) {    // NHWC bf16 scratch
  __shared__ float xs[32][16];
  __shared__ float xm_l[256][17];
  __shared__ float yu_l[256][17];
  __shared__ float red[2][16][9];
  __shared__ float z_l[2][16];

  const int t   = threadIdx.x;
  const int n   = blockIdx.y;
  const int hw0 = blockIdx.x * 16;

  float acc[16];
  #pragma unroll
  for (int i = 0; i < 16; ++i) acc[i] = 0.f;

  const float* xb = x + (size_t)n * CIN * HW + hw0;

  for (int kc = 0; kc < CIN; kc += 32) {
    {
      int e = t, k = e >> 4, p = e & 15;
      xs[k][p] = xb[(kc + k) * HW + p];
      e = t + 256; k = e >> 4; p = e & 15;
      xs[k][p] = xb[(kc + k) * HW + p];
    }
    __syncthreads();
    const float4* wr = (const float4*)(conv1_w + t * CIN + kc);
    #pragma unroll
    for (int i = 0; i < 8; ++i) {
      float4 wv = wr[i];
      #pragma unroll
      for (int kk = 0; kk < 4; ++kk) {
        float wk = (kk == 0) ? wv.x : (kk == 1) ? wv.y : (kk == 2) ? wv.z : wv.w;
        const float4* xr4 = (const float4*)&xs[i * 4 + kk][0];
        #pragma unroll
        for (int j = 0; j < 4; ++j) {
          float4 xv = xr4[j];
          acc[j*4+0] = fmaf(wk, xv.x, acc[j*4+0]);
          acc[j*4+1] = fmaf(wk, xv.y, acc[j*4+1]);
          acc[j*4+2] = fmaf(wk, xv.z, acc[j*4+2]);
          acc[j*4+3] = fmaf(wk, xv.w, acc[j*4+3]);
        }
      }
    }
    __syncthreads();
  }

  float sc = g1[t] * rsqrtf(v1[t] + EPS);
  float sh = b1[t] - m1[t] * sc;
  float xm[16], yv[16];
  #pragma unroll
  for (int p = 0; p < 16; ++p) xm[p] = fmaf(acc[p], sc, sh);

  const float* yb = y + ((size_t)n * MID + t) * 784;
  #pragma unroll
  for (int p = 0; p < 16; ++p) {
    int pix = hw0 + p;
    int hh = pix / 56;
    int ww = pix - hh * 56;
    yv[p] = yb[(hh >> 1) * 28 + (ww >> 1)];
  }

  #pragma unroll
  for (int p = 0; p < 16; ++p) { xm_l[t][p] = xm[p]; yu_l[t][p] = yv[p]; }
  __syncthreads();

  {
    int o = t >> 7, p = (t >> 3) & 15, seg = t & 7;
    const float* aw = att_w + o * 512 + seg * 32;
    float s = 0.f;
    #pragma unroll 8
    for (int i = 0; i < 32; ++i) {
      int mm = seg * 32 + i;
      s = fmaf(aw[i], xm_l[mm][p], s);
      s = fmaf(aw[256 + i], yu_l[mm][p], s);
    }
    red[o][p][seg] = s;
  }
  __syncthreads();
  if (t < 32) {
    int o = t >> 4, p = t & 15;
    float s = att_b[o];
    #pragma unroll
    for (int g = 0; g < 8; ++g) s += red[o][p][g];
    z_l[o][p] = 1.f / (1.f + expf(-s));
  }
  __syncthreads();

  float xf[16];
  #pragma unroll
  for (int p = 0; p < 16; ++p) xf[p] = xm[p] * z_l[0][p] + yv[p] * z_l[1][p];

  float* ob = xf_out + ((size_t)n * MID + t) * HW + hw0;
  #pragma unroll
  for (int j = 0; j < 4; ++j) {
    float4 v; v.x = xf[j*4]; v.y = xf[j*4+1]; v.z = xf[j*4+2]; v.w = xf[j*4+3];
    ((float4*)ob)[j] = v;
  }
  unsigned short* nb = xf_bf + ((size_t)n * HW + hw0) * MID + t;
  #pragma unroll
  for (int p = 0; p < 16; ++p) nb[p * MID] = f2bf(xf[p]);
}

// ---------------- K2: 3x3 conv -> 18 offset channels, bf16 MFMA ----------------
#define K2P  32
#define K2SP 264

__global__ __launch_bounds__(256) void k2_offconv_mfma(
    const unsigned short* __restrict__ xf_bf,
    const unsigned short* __restrict__ wk2,
    float* __restrict__ off_out) {     // [n][pix][18]
  __shared__ unsigned short S[K2P * K2SP];   // 16,896 B
  __shared__ float red2[2][K2P][19];         //  4,864 B

  const int t    = threadIdx.x;
  const int n    = blockIdx.x / 98;
  const int pix0 = (blockIdx.x % 98) * K2P;

  const int l  = t & 63;
  const int lo = l & 15;
  const int hi = l >> 4;
  const int w  = t >> 6;
  const int pt = w & 1;     // pixel tile (16)
  const int kh = w >> 1;    // K half within each tap

  floatx4 acc0 = {0.f, 0.f, 0.f, 0.f};
  floatx4 acc1 = {0.f, 0.f, 0.f, 0.f};

  // staging role: thread -> (pixel p, c-chunk cg)
  const int p   = t >> 3;
  const int cg  = t & 7;
  const int pix = pix0 + p;
  const int hh  = pix / 56;
  const int ww  = pix - hh * 56;

  const short8* wb8 = (const short8*)wk2;

  for (int tap = 0; tap < 9; ++tap) {
    const int ky = tap / 3, kx = tap - (tap / 3) * 3;
    const int yy = hh - 1 + ky, xx = ww - 1 + kx;
    const bool valid = ((unsigned)yy < 56u) && ((unsigned)xx < 56u);
    const int src = ((n * HW) + yy * 56 + xx) << 8;

    __syncthreads();
    #pragma unroll
    for (int g = 0; g < 4; ++g) {
      const int c0 = g * 64 + cg * 8;
      short8 v = (short8){0,0,0,0,0,0,0,0};
      if (valid) v = *(const short8*)(xf_bf + src + c0);
      *(short8*)&S[p * K2SP + c0] = v;
    }
    __syncthreads();

    #pragma unroll
    for (int s = 0; s < 4; ++s) {
      const int kst = kh * 4 + s;          // K32-step within tap (0..7)
      const int ks  = tap * 8 + kst;       // global K32-step (0..71)
      short8 bfrag = *(const short8*)&S[(pt * 16 + lo) * K2SP + kst * 32 + hi * 8];
      short8 a0 = wb8[(0 * 72 + ks) * 64 + l];
      short8 a1 = wb8[(1 * 72 + ks) * 64 + l];
      acc0 = __builtin_amdgcn_mfma_f32_16x16x32_bf16(a0, bfrag, acc0, 0, 0, 0);
      acc1 = __builtin_amdgcn_mfma_f32_16x16x32_bf16(a1, bfrag, acc1, 0, 0, 0);
    }
  }

  // cross-wave K reduction. C/D: row = hi*4+r (o within tile), col = lo (pixel)
  #pragma unroll
  for (int r = 0; r < 4; ++r) {
    int row = hi * 4 + r;
    red2[kh][pt * 16 + lo][row] = acc0[r];
    int o1 = 16 + row;
    if (o1 < 18) red2[kh][pt * 16 + lo][o1] = acc1[r];
  }
  __syncthreads();
  for (int e = t; e < K2P * 18; e += 256) {
    int pp = e / 18, oo = e - pp * 18;
    float sres = red2[0][pp][oo] + red2[1][pp][oo];
    off_out[((size_t)(n * HW) + pix0) * 18 + e] = sres;
  }
}

// ---------------- K3: deformable conv + BN2, bf16 MFMA ----------------
#define PB 32
#define SPITCH 264

__global__ __launch_bounds__(256) void k3_deform_mfma(
    const unsigned short* __restrict__ xf_bf, const float* __restrict__ off_in,
    const unsigned short* __restrict__ wbf,
    const float* __restrict__ g2, const float* __restrict__ b2,
    const float* __restrict__ m2, const float* __restrict__ v2,
    float* __restrict__ out) {
  __shared__ unsigned short S[PB * SPITCH];   // 16,896 B
  __shared__ float cw[288][4];
  __shared__ int   ad[288][4];
  __shared__ float offs[PB * 18];

  const int t    = threadIdx.x;
  const int n    = blockIdx.x / 98;
  const int pix0 = (blockIdx.x % 98) * PB;

  for (int e = t; e < PB * 18; e += 256)
    offs[e] = off_in[((size_t)(n * HW) + pix0) * 18 + e];
  __syncthreads();

  for (int e = t; e < 288; e += 256) {
    int p = e / 9, k = e - p * 9;
    int ky = k / 3, kx = k - ky * 3;
    int pix = pix0 + p;
    int hh = pix / 56, ww = pix - hh * 56;
    float sy = (float)(hh - 1 + ky) + offs[p * 18 + 2 * k];
    float sx = (float)(ww - 1 + kx) + offs[p * 18 + 2 * k + 1];
    float y0f = floorf(sy), x0f = floorf(sx);
    int y0 = (int)y0f, x0 = (int)x0f;
    float wy = sy - y0f, wx = sx - x0f;
    float w00 = (1.f - wy) * (1.f - wx), w01 = (1.f - wy) * wx;
    float w10 = wy * (1.f - wx),         w11 = wy * wx;
    bool yv0 = (unsigned)y0 < 56u, yv1 = (unsigned)(y0 + 1) < 56u;
    bool xv0 = (unsigned)x0 < 56u, xv1 = (unsigned)(x0 + 1) < 56u;
    int base = n * HW;
    ad[e][0] = (yv0 && xv0) ? (base + y0 * 56 + x0) * 256         : 0;
    ad[e][1] = (yv0 && xv1) ? (base + y0 * 56 + x0 + 1) * 256     : 0;
    ad[e][2] = (yv1 && xv0) ? (base + (y0+1) * 56 + x0) * 256     : 0;
    ad[e][3] = (yv1 && xv1) ? (base + (y0+1) * 56 + x0 + 1) * 256 : 0;
    cw[e][0] = (yv0 && xv0) ? w00 : 0.f;
    cw[e][1] = (yv0 && xv1) ? w01 : 0.f;
    cw[e][2] = (yv1 && xv0) ? w10 : 0.f;
    cw[e][3] = (yv1 && xv1) ? w11 : 0.f;
  }

  const int w  = t >> 6;
  const int l  = t & 63;
  const int lo = l & 15;
  const int hi = l >> 4;

  floatx4 acc[4][2];
  #pragma unroll
  for (int i = 0; i < 4; ++i)
    #pragma unroll
    for (int j = 0; j < 2; ++j)
      acc[i][j] = (floatx4){0.f, 0.f, 0.f, 0.f};

  const short8* wbase = (const short8*)wbf;

  // staging role: thread -> (pixel p, c-chunk cg)
  const int sp_p  = t >> 3;
  const int sp_cg = t & 7;

  for (int tap = 0; tap < 9; ++tap) {
    __syncthreads();
    {
      const int s = sp_p * 9 + tap;
      const int a0 = ad[s][0], a1 = ad[s][1], a2 = ad[s][2], a3 = ad[s][3];
      const float w0 = cw[s][0], w1 = cw[s][1], w2 = cw[s][2], w3 = cw[s][3];
      #pragma unroll
      for (int g = 0; g < 4; ++g) {
        const int c0 = g * 64 + sp_cg * 8;
        short8 va = *(const short8*)(xf_bf + a0 + c0);
        short8 vb = *(const short8*)(xf_bf + a1 + c0);
        short8 vc = *(const short8*)(xf_bf + a2 + c0);
        short8 vd = *(const short8*)(xf_bf + a3 + c0);
        unsigned int pk[4];
        #pragma unroll
        for (int u = 0; u < 4; ++u) {
          float f0 = w0 * bf2f((unsigned short)va[2*u]);
          f0 = fmaf(w1, bf2f((unsigned short)vb[2*u]), f0);
          f0 = fmaf(w2, bf2f((unsigned short)vc[2*u]), f0);
          f0 = fmaf(w3, bf2f((unsigned short)vd[2*u]), f0);
          float f1 = w0 * bf2f((unsigned short)va[2*u+1]);
          f1 = fmaf(w1, bf2f((unsigned short)vb[2*u+1]), f1);
          f1 = fmaf(w2, bf2f((unsigned short)vc[2*u+1]), f1);
          f1 = fmaf(w3, bf2f((unsigned short)vd[2*u+1]), f1);
          pk[u] = pack2bf(f0, f1);
        }
        uint4 ov; ov.x = pk[0]; ov.y = pk[1]; ov.z = pk[2]; ov.w = pk[3];
        *(uint4*)&S[sp_p * SPITCH + c0] = ov;
      }
    }
    __syncthreads();

    #pragma unroll
    for (int ks = 0; ks < 8; ++ks) {
      int rb = tap * 32 + ks * 4 + hi;
      const short8* wp = wbase + ((rb << 8) + (w << 6) + lo);
      short8 wa0 = wp[0];
      short8 wa1 = wp[16];
      short8 wa2 = wp[32];
      short8 wa3 = wp[48];
      const unsigned short* sp = &S[lo * SPITCH + (ks << 5) + (hi << 3)];
      short8 sb0 = *(const short8*)sp;
      short8 sb1 = *(const short8*)(sp + 16 * SPITCH);
      acc[0][0] = __builtin_amdgcn_mfma_f32_16x16x32_bf16(wa0, sb0, acc[0][0], 0, 0, 0);
      acc[0][1] = __builtin_amdgcn_mfma_f32_16x16x32_bf16(wa0, sb1, acc[0][1], 0, 0, 0);
      acc[1][0] = __builtin_amdgcn_mfma_f32_16x16x32_bf16(wa1, sb0, acc[1][0], 0, 0, 0);
      acc[1][1] = __builtin_amdgcn_mfma_f32_16x16x32_bf16(wa1, sb1, acc[1][1], 0, 0, 0);
      acc[2][0] = __builtin_amdgcn_mfma_f32_16x16x32_bf16(wa2, sb0, acc[2][0], 0, 0, 0);
      acc[2][1] = __builtin_amdgcn_mfma_f32_16x16x32_bf16(wa2, sb1, acc[2][1], 0, 0, 0);
      acc[3][0] = __builtin_amdgcn_mfma_f32_16x16x32_bf16(wa3, sb0, acc[3][0], 0, 0, 0);
      acc[3][1] = __builtin_amdgcn_mfma_f32_16x16x32_bf16(wa3, sb1, acc[3][1], 0, 0, 0);
    }
  }

  #pragma unroll
  for (int i = 0; i < 4; ++i) {
    #pragma unroll
    for (int r = 0; r < 4; ++r) {
      int o = (w << 6) + (i << 4) + (hi << 2) + r;
      float scv = g2[o] * rsqrtf(v2[o] + EPS);
      float shv = b2[o] - m2[o] * scv;
      float* ob = out + ((size_t)(n * OUTC + o)) * HW + pix0;
      ob[lo]      = fmaf(acc[i][0][r], scv, shv);
      ob[16 + lo] = fmaf(acc[i][1][r], scv, shv);
    }
  }
}

extern "C" void kernel_launch(void* const* d_in, const int* in_sizes, int n_in,
                              void* d_out, int out_size, void* d_ws, size_t ws_size,
                              hipStream_t stream) {
  const float* x       = (const float*)d_in[0];
  const float* y       = (const float*)d_in[1];
  const float* conv1_w = (const float*)d_in[2];
  const float* g1      = (const float*)d_in[3];
  const float* b1      = (const float*)d_in[4];
  const float* m1      = (const float*)d_in[5];
  const float* v1      = (const float*)d_in[6];
  const float* att_w   = (const float*)d_in[7];
  const float* att_b   = (const float*)d_in[8];
  const float* off_w   = (const float*)d_in[9];
  const float* dcn_w   = (const float*)d_in[10];
  const float* g2      = (const float*)d_in[11];
  const float* b2      = (const float*)d_in[12];
  const float* m2      = (const float*)d_in[13];
  const float* v2      = (const float*)d_in[14];

  float* out    = (float*)d_out;
  float* xf_out = out + (size_t)N_ * OUTC * HW;

  char* ws = (char*)d_ws;
  unsigned short* xf_bf   = (unsigned short*)ws;
  float*          off_buf = (float*)(ws + XF_BF_BYTES);
  unsigned short* wbf     = (unsigned short*)(ws + XF_BF_BYTES + OFF_BYTES);
  unsigned short* wk2     = (unsigned short*)(ws + XF_BF_BYTES + OFF_BYTES + WBF_BYTES);

  hipLaunchKernelGGL(prep_wbf, dim3(2304), dim3(256), 0, stream, dcn_w, wbf);
  hipLaunchKernelGGL(prep_wk2, dim3(288), dim3(256), 0, stream, off_w, wk2);
  hipLaunchKernelGGL(k1_conv1_attn, dim3(196, N_), dim3(256), 0, stream,
                     x, y, conv1_w, g1, b1, m1, v1, att_w, att_b, xf_out, xf_bf);
  hipLaunchKernelGGL(k2_offconv_mfma, dim3(784), dim3(256), 0, stream,
                     xf_bf, wk2, off_buf);
  hipLaunchKernelGGL(k3_deform_mfma, dim3(784), dim3(256), 0, stream,
                     xf_bf, off_buf, wbf, g2, b2, m2, v2, out);
}

// Round 4
// 299.594 us; speedup vs baseline: 9.1564x; 1.3466x over previous
//
#include <hip/hip_runtime.h>
#include <math.h>

#define N_   8
#define CIN  512
#define MID  256
#define OUTC 256
#define H_   56
#define W_   56
#define HW   3136
#define EPS  1e-5f

typedef __attribute__((ext_vector_type(8))) short short8;
typedef __attribute__((ext_vector_type(4))) float floatx4;

__device__ __forceinline__ float bf2f(unsigned short b) {
  unsigned int u = ((unsigned int)b) << 16;
  return __builtin_bit_cast(float, u);
}
__device__ __forceinline__ unsigned short f2bf(float f) {
  unsigned int u = __builtin_bit_cast(unsigned int, f);
  unsigned int r = u + 0x7fffu + ((u >> 16) & 1u);
  return (unsigned short)(r >> 16);
}
__device__ __forceinline__ unsigned int pack2bf(float f0, float f1) {
  unsigned int u0 = __builtin_bit_cast(unsigned int, f0);
  unsigned int u1 = __builtin_bit_cast(unsigned int, f1);
  u0 += 0x7fffu + ((u0 >> 16) & 1u);
  u1 += 0x7fffu + ((u1 >> 16) & 1u);
  return (u0 >> 16) | (u1 & 0xffff0000u);
}

// workspace layout (bytes)
#define XF_BF_BYTES  (N_*HW*MID*2)        // 12,845,056
#define OFF_BYTES    (N_*HW*18*4)         //  1,806,336
#define WBF_BYTES    (256*2304*2)         //  1,179,648
#define WK2_BYTES    (2*72*64*8*2)        //    147,456
#define W1_BYTES     (64*256*8*2)         //    262,144
#define XB_BYTES     ((size_t)N_*HW*CIN*2)// 25,690,112

// ---------------- prep: dcn_w [O][C][9] -> wbf bf16 [r/8][o][j] (r = tap*256+c) ----
__global__ __launch_bounds__(256) void prep_wbf(const float* __restrict__ dcn_w,
                                                unsigned short* __restrict__ wbf) {
  int e = blockIdx.x * 256 + threadIdx.x;   // < 589,824
  int rb  = e >> 11;
  int rem = e & 2047;
  int o   = rem >> 3;
  int j   = e & 7;
  int r   = rb * 8 + j;
  int tap = r >> 8;
  int c   = r & 255;
  wbf[e] = f2bf(dcn_w[(o * 256 + c) * 9 + tap]);
}

// ---------------- prep: off_w -> wk2 A-frag layout (M pad 18->32) ----------------
__global__ __launch_bounds__(256) void prep_wk2(const float* __restrict__ off_w,
                                                unsigned short* __restrict__ wk2) {
  int e = blockIdx.x * 256 + threadIdx.x;   // < 73,728
  int j  = e & 7;
  int l  = (e >> 3) & 63;
  int q  = e >> 9;
  int ot = (q >= 72) ? 1 : 0;
  int ks = q - ot * 72;
  int o  = ot * 16 + (l & 15);
  int r  = ks * 32 + ((l >> 4) << 3) + j;
  int tap = r >> 8;
  int c   = r & 255;
  float v = (o < 18) ? off_w[(o * 256 + c) * 9 + tap] : 0.f;
  wk2[e] = f2bf(v);
}

// ---------------- prep: conv1_w [256][512] -> w1bf A-frag [c/8][m][8] ----------------
__global__ __launch_bounds__(256) void prep_w1(const float* __restrict__ conv1_w,
                                               unsigned short* __restrict__ w1bf) {
  int e = blockIdx.x * 256 + threadIdx.x;   // < 131,072
  int rb = e >> 11;
  int m  = (e >> 3) & 255;
  int j  = e & 7;
  int c  = rb * 8 + j;
  w1bf[e] = f2bf(conv1_w[m * 512 + c]);
}

// ---------------- prep: x NCHW fp32 -> xb NHWC bf16 ----------------
#define TP 72
__global__ __launch_bounds__(256) void prep_x(const float* __restrict__ x,
                                              unsigned short* __restrict__ xb) {
  __shared__ unsigned short T[32 * TP];
  const int t  = threadIdx.x;
  const int n  = blockIdx.z;
  const int c0 = blockIdx.y * 32;
  const int p0 = blockIdx.x * 64;

  {
    int c = t >> 3, pg = t & 7;
    const float4* src = (const float4*)(x + ((size_t)(n * CIN + c0 + c)) * HW + p0 + pg * 8);
    float4 v0 = src[0];
    float4 v1 = src[1];
    unsigned int d0 = pack2bf(v0.x, v0.y), d1 = pack2bf(v0.z, v0.w);
    unsigned int d2 = pack2bf(v1.x, v1.y), d3 = pack2bf(v1.z, v1.w);
    uint2 a; a.x = d0; a.y = d1;
    uint2 b; b.x = d2; b.y = d3;
    *(uint2*)&T[c * TP + pg * 8]     = a;
    *(uint2*)&T[c * TP + pg * 8 + 4] = b;
  }
  __syncthreads();
  {
    int p = t >> 2, cq = t & 3;
    unsigned short o8[8];
    #pragma unroll
    for (int j = 0; j < 8; ++j) o8[j] = T[(cq * 8 + j) * TP + p];
    *(short8*)(xb + ((size_t)(n * HW) + p0 + p) * CIN + c0 + cq * 8) = *(short8*)o8;
  }
}

// ---------------- K1: conv1 MFMA GEMM + BN1 + upsample + attention -> xf ----------------
#define K1SP 520   // 512 + 8 pad (bf16 elems)
#define XSP  264   // epilogue Sx pitch

__global__ __launch_bounds__(256) void k1_gemm(
    const unsigned short* __restrict__ xb,
    const unsigned short* __restrict__ w1bf,
    const float* __restrict__ y,
    const float* __restrict__ g1, const float* __restrict__ b1,
    const float* __restrict__ m1, const float* __restrict__ v1,
    const float* __restrict__ att_w, const float* __restrict__ att_b,
    float* __restrict__ xf_out,              // NCHW fp32 (second output)
    unsigned short* __restrict__ xf_bf) {    // NHWC bf16 scratch
  __shared__ unsigned short S[32 * K1SP];    // 33,280 B
  __shared__ float part[2][32][17];          //  4,352 B
  __shared__ float zz[2][32];

  const int t    = threadIdx.x;
  const int n    = blockIdx.x / 98;
  const int pix0 = (blockIdx.x % 98) * 32;

  // stage B: 32 pixels x 512 channels of xb
  {
    const int p = t >> 3, cg = t & 7;
    const short8* src = (const short8*)(xb + ((size_t)(n * HW) + pix0 + p) * CIN) + cg * 8;
    short8* dst = (short8*)&S[p * K1SP + cg * 64];
    #pragma unroll
    for (int j = 0; j < 8; ++j) dst[j] = src[j];
  }
  __syncthreads();

  const int w  = t >> 6;
  const int l  = t & 63;
  const int lo = l & 15;
  const int hi = l >> 4;

  floatx4 acc[4][2];
  #pragma unroll
  for (int i = 0; i < 4; ++i)
    #pragma unroll
    for (int j = 0; j < 2; ++j)
      acc[i][j] = (floatx4){0.f, 0.f, 0.f, 0.f};

  const short8* wbase = (const short8*)w1bf;

  #pragma unroll 4
  for (int ks = 0; ks < 16; ++ks) {
    int rb = ks * 4 + hi;
    const short8* wp = wbase + ((rb << 8) + (w << 6) + lo);
    short8 wa0 = wp[0];
    short8 wa1 = wp[16];
    short8 wa2 = wp[32];
    short8 wa3 = wp[48];
    const unsigned short* sp = &S[lo * K1SP + (ks << 5) + (hi << 3)];
    short8 sb0 = *(const short8*)sp;
    short8 sb1 = *(const short8*)(sp + 16 * K1SP);
    acc[0][0] = __builtin_amdgcn_mfma_f32_16x16x32_bf16(wa0, sb0, acc[0][0], 0, 0, 0);
    acc[0][1] = __builtin_amdgcn_mfma_f32_16x16x32_bf16(wa0, sb1, acc[0][1], 0, 0, 0);
    acc[1][0] = __builtin_amdgcn_mfma_f32_16x16x32_bf16(wa1, sb0, acc[1][0], 0, 0, 0);
    acc[1][1] = __builtin_amdgcn_mfma_f32_16x16x32_bf16(wa1, sb1, acc[1][1], 0, 0, 0);
    acc[2][0] = __builtin_amdgcn_mfma_f32_16x16x32_bf16(wa2, sb0, acc[2][0], 0, 0, 0);
    acc[2][1] = __builtin_amdgcn_mfma_f32_16x16x32_bf16(wa2, sb1, acc[2][1], 0, 0, 0);
    acc[3][0] = __builtin_amdgcn_mfma_f32_16x16x32_bf16(wa3, sb0, acc[3][0], 0, 0, 0);
    acc[3][1] = __builtin_amdgcn_mfma_f32_16x16x32_bf16(wa3, sb1, acc[3][1], 0, 0, 0);
  }

  // --- epilogue: BN1, yu, attention ---
  const int pixA = pix0 + lo, pixB = pixA + 16;
  const int hA = pixA / 56, wxA = pixA - hA * 56;
  const int hB = pixB / 56, wxB = pixB - hB * 56;
  const int yoA = (hA >> 1) * 28 + (wxA >> 1);
  const int yoB = (hB >> 1) * 28 + (wxB >> 1);
  const float* yb = y + (size_t)n * MID * 784;

  float xmv[4][2][4];
  float s0A = 0.f, s0B = 0.f, s1A = 0.f, s1B = 0.f;
  #pragma unroll
  for (int i = 0; i < 4; ++i) {
    #pragma unroll
    for (int r = 0; r < 4; ++r) {
      int o = (w << 6) + (i << 4) + (hi << 2) + r;
      float sc = g1[o] * rsqrtf(v1[o] + EPS);
      float sh = fmaf(-m1[o], sc, b1[o]);
      float xA = fmaf(acc[i][0][r], sc, sh);
      float xB = fmaf(acc[i][1][r], sc, sh);
      xmv[i][0][r] = xA; xmv[i][1][r] = xB;
      float yA = yb[o * 784 + yoA];
      float yB = yb[o * 784 + yoB];
      float a0x = att_w[o], a0y = att_w[256 + o];
      float a1x = att_w[512 + o], a1y = att_w[768 + o];
      s0A = fmaf(a0x, xA, fmaf(a0y, yA, s0A));
      s0B = fmaf(a0x, xB, fmaf(a0y, yB, s0B));
      s1A = fmaf(a1x, xA, fmaf(a1y, yA, s1A));
      s1B = fmaf(a1x, xB, fmaf(a1y, yB, s1B));
    }
  }
  {
    int slot = (w << 2) + hi;
    part[0][lo][slot]      = s0A;
    part[0][16 + lo][slot] = s0B;
    part[1][lo][slot]      = s1A;
    part[1][16 + lo][slot] = s1B;
  }
  __syncthreads();
  if (t < 64) {
    int a = t >> 5, pp = t & 31;
    float s = att_b[a];
    #pragma unroll
    for (int g = 0; g < 16; ++g) s += part[a][pp][g];
    zz[a][pp] = 1.f / (1.f + expf(-s));
  }
  __syncthreads();

  {
    unsigned short* Sx = S;   // reuse (all GEMM reads of S are done)
    float z0A = zz[0][lo], z0B = zz[0][16 + lo];
    float z1A = zz[1][lo], z1B = zz[1][16 + lo];
    #pragma unroll
    for (int i = 0; i < 4; ++i) {
      #pragma unroll
      for (int r = 0; r < 4; ++r) {
        int o = (w << 6) + (i << 4) + (hi << 2) + r;
        float yA = yb[o * 784 + yoA];
        float yB = yb[o * 784 + yoB];
        float xfA = fmaf(xmv[i][0][r], z0A, yA * z1A);
        float xfB = fmaf(xmv[i][1][r], z0B, yB * z1B);
        float* ob = xf_out + (size_t)(n * MID + o) * HW;
        ob[pixA] = xfA;
        ob[pixB] = xfB;
        Sx[lo * XSP + o]        = f2bf(xfA);
        Sx[(16 + lo) * XSP + o] = f2bf(xfB);
      }
    }
  }
  __syncthreads();
  {
    const unsigned short* Sx = S;
    const int p = t >> 3, cg = t & 7;
    unsigned short* dst = xf_bf + ((size_t)(n * HW) + pix0 + p) * MID + cg * 32;
    #pragma unroll
    for (int j = 0; j < 4; ++j)
      *(short8*)(dst + j * 8) = *(const short8*)&Sx[p * XSP + cg * 32 + j * 8];
  }
}

// ---------------- K2: 3x3 conv -> 18 offset channels, bf16 MFMA ----------------
#define K2P  32
#define K2SP 264

__global__ __launch_bounds__(256) void k2_offconv_mfma(
    const unsigned short* __restrict__ xf_bf,
    const unsigned short* __restrict__ wk2,
    float* __restrict__ off_out) {
  __shared__ unsigned short S[K2P * K2SP];
  __shared__ float red2[2][K2P][19];

  const int t    = threadIdx.x;
  const int n    = blockIdx.x / 98;
  const int pix0 = (blockIdx.x % 98) * K2P;

  const int l  = t & 63;
  const int lo = l & 15;
  const int hi = l >> 4;
  const int w  = t >> 6;
  const int pt = w & 1;
  const int kh = w >> 1;

  floatx4 acc0 = {0.f, 0.f, 0.f, 0.f};
  floatx4 acc1 = {0.f, 0.f, 0.f, 0.f};

  const int p   = t >> 3;
  const int cg  = t & 7;
  const int pix = pix0 + p;
  const int hh  = pix / 56;
  const int ww  = pix - hh * 56;

  const short8* wb8 = (const short8*)wk2;

  for (int tap = 0; tap < 9; ++tap) {
    const int ky = tap / 3, kx = tap - (tap / 3) * 3;
    const int yy = hh - 1 + ky, xx = ww - 1 + kx;
    const bool valid = ((unsigned)yy < 56u) && ((unsigned)xx < 56u);
    const int src = ((n * HW) + yy * 56 + xx) << 8;

    __syncthreads();
    #pragma unroll
    for (int g = 0; g < 4; ++g) {
      const int c0 = g * 64 + cg * 8;
      short8 v = (short8){0,0,0,0,0,0,0,0};
      if (valid) v = *(const short8*)(xf_bf + src + c0);
      *(short8*)&S[p * K2SP + c0] = v;
    }
    __syncthreads();

    #pragma unroll
    for (int s = 0; s < 4; ++s) {
      const int kst = kh * 4 + s;
      const int ks  = tap * 8 + kst;
      short8 bfrag = *(const short8*)&S[(pt * 16 + lo) * K2SP + kst * 32 + hi * 8];
      short8 a0 = wb8[(0 * 72 + ks) * 64 + l];
      short8 a1 = wb8[(1 * 72 + ks) * 64 + l];
      acc0 = __builtin_amdgcn_mfma_f32_16x16x32_bf16(a0, bfrag, acc0, 0, 0, 0);
      acc1 = __builtin_amdgcn_mfma_f32_16x16x32_bf16(a1, bfrag, acc1, 0, 0, 0);
    }
  }

  #pragma unroll
  for (int r = 0; r < 4; ++r) {
    int row = hi * 4 + r;
    red2[kh][pt * 16 + lo][row] = acc0[r];
    int o1 = 16 + row;
    if (o1 < 18) red2[kh][pt * 16 + lo][o1] = acc1[r];
  }
  __syncthreads();
  for (int e = t; e < K2P * 18; e += 256) {
    int pp = e / 18, oo = e - pp * 18;
    float sres = red2[0][pp][oo] + red2[1][pp][oo];
    off_out[((size_t)(n * HW) + pix0) * 18 + e] = sres;
  }
}

// ---------------- K3: deformable conv + BN2, bf16 MFMA ----------------
#define PB 32
#define SPITCH 264

__global__ __launch_bounds__(256) void k3_deform_mfma(
    const unsigned short* __restrict__ xf_bf, const float* __restrict__ off_in,
    const unsigned short* __restrict__ wbf,
    const float* __restrict__ g2, const float* __restrict__ b2,
    const float* __restrict__ m2, const float* __restrict__ v2,
    float* __restrict__ out) {
  __shared__ unsigned short S[PB * SPITCH];
  __shared__ float cw[288][4];
  __shared__ int   ad[288][4];
  __shared__ float offs[PB * 18];

  const int t    = threadIdx.x;
  const int n    = blockIdx.x / 98;
  const int pix0 = (blockIdx.x % 98) * PB;

  for (int e = t; e < PB * 18; e += 256)
    offs[e] = off_in[((size_t)(n * HW) + pix0) * 18 + e];
  __syncthreads();

  for (int e = t; e < 288; e += 256) {
    int p = e / 9, k = e - p * 9;
    int ky = k / 3, kx = k - ky * 3;
    int pix = pix0 + p;
    int hh = pix / 56, ww = pix - hh * 56;
    float sy = (float)(hh - 1 + ky) + offs[p * 18 + 2 * k];
    float sx = (float)(ww - 1 + kx) + offs[p * 18 + 2 * k + 1];
    float y0f = floorf(sy), x0f = floorf(sx);
    int y0 = (int)y0f, x0 = (int)x0f;
    float wy = sy - y0f, wx = sx - x0f;
    float w00 = (1.f - wy) * (1.f - wx), w01 = (1.f - wy) * wx;
    float w10 = wy * (1.f - wx),         w11 = wy * wx;
    bool yv0 = (unsigned)y0 < 56u, yv1 = (unsigned)(y0 + 1) < 56u;
    bool xv0 = (unsigned)x0 < 56u, xv1 = (unsigned)(x0 + 1) < 56u;
    int base = n * HW;
    ad[e][0] = (yv0 && xv0) ? (base + y0 * 56 + x0) * 256         : 0;
    ad[e][1] = (yv0 && xv1) ? (base + y0 * 56 + x0 + 1) * 256     : 0;
    ad[e][2] = (yv1 && xv0) ? (base + (y0+1) * 56 + x0) * 256     : 0;
    ad[e][3] = (yv1 && xv1) ? (base + (y0+1) * 56 + x0 + 1) * 256 : 0;
    cw[e][0] = (yv0 && xv0) ? w00 : 0.f;
    cw[e][1] = (yv0 && xv1) ? w01 : 0.f;
    cw[e][2] = (yv1 && xv0) ? w10 : 0.f;
    cw[e][3] = (yv1 && xv1) ? w11 : 0.f;
  }

  const int w  = t >> 6;
  const int l  = t & 63;
  const int lo = l & 15;
  const int hi = l >> 4;

  floatx4 acc[4][2];
  #pragma unroll
  for (int i = 0; i < 4; ++i)
    #pragma unroll
    for (int j = 0; j < 2; ++j)
      acc[i][j] = (floatx4){0.f, 0.f, 0.f, 0.f};

  const short8* wbase = (const short8*)wbf;

  const int sp_p  = t >> 3;
  const int sp_cg = t & 7;

  for (int tap = 0; tap < 9; ++tap) {
    __syncthreads();
    {
      const int s = sp_p * 9 + tap;
      const int a0 = ad[s][0], a1 = ad[s][1], a2 = ad[s][2], a3 = ad[s][3];
      const float w0 = cw[s][0], w1 = cw[s][1], w2 = cw[s][2], w3 = cw[s][3];
      #pragma unroll
      for (int g = 0; g < 4; ++g) {
        const int c0 = g * 64 + sp_cg * 8;
        short8 va = *(const short8*)(xf_bf + a0 + c0);
        short8 vb = *(const short8*)(xf_bf + a1 + c0);
        short8 vc = *(const short8*)(xf_bf + a2 + c0);
        short8 vd = *(const short8*)(xf_bf + a3 + c0);
        unsigned int pk[4];
        #pragma unroll
        for (int u = 0; u < 4; ++u) {
          float f0 = w0 * bf2f((unsigned short)va[2*u]);
          f0 = fmaf(w1, bf2f((unsigned short)vb[2*u]), f0);
          f0 = fmaf(w2, bf2f((unsigned short)vc[2*u]), f0);
          f0 = fmaf(w3, bf2f((unsigned short)vd[2*u]), f0);
          float f1 = w0 * bf2f((unsigned short)va[2*u+1]);
          f1 = fmaf(w1, bf2f((unsigned short)vb[2*u+1]), f1);
          f1 = fmaf(w2, bf2f((unsigned short)vc[2*u+1]), f1);
          f1 = fmaf(w3, bf2f((unsigned short)vd[2*u+1]), f1);
          pk[u] = pack2bf(f0, f1);
        }
        uint4 ov; ov.x = pk[0]; ov.y = pk[1]; ov.z = pk[2]; ov.w = pk[3];
        *(uint4*)&S[sp_p * SPITCH + c0] = ov;
      }
    }
    __syncthreads();

    #pragma unroll
    for (int ks = 0; ks < 8; ++ks) {
      int rb = tap * 32 + ks * 4 + hi;
      const short8* wp = wbase + ((rb << 8) + (w << 6) + lo);
      short8 wa0 = wp[0];
      short8 wa1 = wp[16];
      short8 wa2 = wp[32];
      short8 wa3 = wp[48];
      const unsigned short* sp = &S[lo * SPITCH + (ks << 5) + (hi << 3)];
      short8 sb0 = *(const short8*)sp;
      short8 sb1 = *(const short8*)(sp + 16 * SPITCH);
      acc[0][0] = __builtin_amdgcn_mfma_f32_16x16x32_bf16(wa0, sb0, acc[0][0], 0, 0, 0);
      acc[0][1] = __builtin_amdgcn_mfma_f32_16x16x32_bf16(wa0, sb1, acc[0][1], 0, 0, 0);
      acc[1][0] = __builtin_amdgcn_mfma_f32_16x16x32_bf16(wa1, sb0, acc[1][0], 0, 0, 0);
      acc[1][1] = __builtin_amdgcn_mfma_f32_16x16x32_bf16(wa1, sb1, acc[1][1], 0, 0, 0);
      acc[2][0] = __builtin_amdgcn_mfma_f32_16x16x32_bf16(wa2, sb0, acc[2][0], 0, 0, 0);
      acc[2][1] = __builtin_amdgcn_mfma_f32_16x16x32_bf16(wa2, sb1, acc[2][1], 0, 0, 0);
      acc[3][0] = __builtin_amdgcn_mfma_f32_16x16x32_bf16(wa3, sb0, acc[3][0], 0, 0, 0);
      acc[3][1] = __builtin_amdgcn_mfma_f32_16x16x32_bf16(wa3, sb1, acc[3][1], 0, 0, 0);
    }
  }

  #pragma unroll
  for (int i = 0; i < 4; ++i) {
    #pragma unroll
    for (int r = 0; r < 4; ++r) {
      int o = (w << 6) + (i << 4) + (hi << 2) + r;
      float scv = g2[o] * rsqrtf(v2[o] + EPS);
      float shv = b2[o] - m2[o] * scv;
      float* ob = out + ((size_t)(n * OUTC + o)) * HW + pix0;
      ob[lo]      = fmaf(acc[i][0][r], scv, shv);
      ob[16 + lo] = fmaf(acc[i][1][r], scv, shv);
    }
  }
}

extern "C" void kernel_launch(void* const* d_in, const int* in_sizes, int n_in,
                              void* d_out, int out_size, void* d_ws, size_t ws_size,
                              hipStream_t stream) {
  const float* x       = (const float*)d_in[0];
  const float* y       = (const float*)d_in[1];
  const float* conv1_w = (const float*)d_in[2];
  const float* g1      = (const float*)d_in[3];
  const float* b1      = (const float*)d_in[4];
  const float* m1      = (const float*)d_in[5];
  const float* v1      = (const float*)d_in[6];
  const float* att_w   = (const float*)d_in[7];
  const float* att_b   = (const float*)d_in[8];
  const float* off_w   = (const float*)d_in[9];
  const float* dcn_w   = (const float*)d_in[10];
  const float* g2      = (const float*)d_in[11];
  const float* b2      = (const float*)d_in[12];
  const float* m2      = (const float*)d_in[13];
  const float* v2      = (const float*)d_in[14];

  float* out    = (float*)d_out;
  float* xf_out = out + (size_t)N_ * OUTC * HW;

  char* ws = (char*)d_ws;
  unsigned short* xf_bf   = (unsigned short*)ws;
  float*          off_buf = (float*)(ws + XF_BF_BYTES);
  unsigned short* wbf     = (unsigned short*)(ws + XF_BF_BYTES + OFF_BYTES);
  unsigned short* wk2     = (unsigned short*)(ws + XF_BF_BYTES + OFF_BYTES + WBF_BYTES);
  unsigned short* w1bf    = (unsigned short*)(ws + XF_BF_BYTES + OFF_BYTES + WBF_BYTES + WK2_BYTES);
  unsigned short* xb      = (unsigned short*)(ws + XF_BF_BYTES + OFF_BYTES + WBF_BYTES + WK2_BYTES + W1_BYTES);

  hipLaunchKernelGGL(prep_wbf, dim3(2304), dim3(256), 0, stream, dcn_w, wbf);
  hipLaunchKernelGGL(prep_wk2, dim3(288), dim3(256), 0, stream, off_w, wk2);
  hipLaunchKernelGGL(prep_w1, dim3(512), dim3(256), 0, stream, conv1_w, w1bf);
  hipLaunchKernelGGL(prep_x, dim3(49, 16, N_), dim3(256), 0, stream, x, xb);
  hipLaunchKernelGGL(k1_gemm, dim3(784), dim3(256), 0, stream,
                     xb, w1bf, y, g1, b1, m1, v1, att_w, att_b, xf_out, xf_bf);
  hipLaunchKernelGGL(k2_offconv_mfma, dim3(784), dim3(256), 0, stream,
                     xf_bf, wk2, off_buf);
  hipLaunchKernelGGL(k3_deform_mfma, dim3(784), dim3(256), 0, stream,
                     xf_bf, off_buf, wbf, g2, b2, m2, v2, out);
}